// Round 12
// baseline (1231.055 us; speedup 1.0000x reference)
//
#include <hip/hip_runtime.h>
#include <math.h>

#define NPARTS 20
#define BATCH  2048
#define TOTALV 991
#define NEPS   9

#define LOG2E 1.4426950408889634f
#define LN2   0.6931471805599453f
#define NEGBIG -1.0e30f

__constant__ int   c_start[NPARTS] = {0,45,106,149,194,286,320,361,423,467,511,569,611,651,711,752,787,851,879,929};
__constant__ int   c_n[NPARTS]     = {45,61,43,45,92,34,41,62,44,44,58,42,40,60,41,35,64,28,50,62};
__constant__ float c_eps[NEPS]     = {64.0f,16.0f,4.0f,1.0f,0.25f,0.0625f,0.015625f,0.00390625f,0.0025f};

// 4 wave-slots, parts bin-packed (R=4 rows/lane, h=ceil(n/4) lanes/part).
// Region layout: part-row r at region offset r; rows >= n are pads (coords 0,
// terms -1e30 -> exp2 -> 0; pads <= 3 so every chunk has a real row).
//  slot0: p4(h23) p7(16) p19(16) p15(9)         offs 0,92,156,220  (256)
//  slot1: p16(16) p1(16) p13(15) p12(10) p17(7) offs 0,64,128,188,228 (256)
//  slot2: p10(15) p18(13) p0(12) p3(12) p8(11)  offs 0,60,112,160,208 (252)
//  slot3: p9(11) p2(11) p11(11) p6(11) p14(11) p5(9) offs 0,44,88,132,176,220 (256)
// Block = 256 thr = 4 waves = one batch item; wave wv covers slot (wv+b)&3.
__constant__ int c_w_np[4]       = {4,5,5,6};
__constant__ int c_w_part[4][6]  = {{4,7,19,15,0,0},{16,1,13,12,17,0},{10,18,0,3,8,0},{9,2,11,6,14,5}};
__constant__ int c_w_lane0[4][7] = {{0,23,39,55,64,64,64},{0,16,32,47,57,64,64},{0,15,28,40,52,63,64},{0,11,22,33,44,55,64}};
__constant__ int c_w_tb[4][6]    = {{0,92,156,220,0,0},{0,64,128,188,228,0},{0,60,112,160,208,0},{0,44,88,132,176,220}};

#define NROWS 1024

// Online-lse chunk update: 4 w's (w = A·Pk + Tk), chunk max, one rescale.
#define SU(A0,A1,A2, P0,P1,P2,P3, T0,T1,T2,T3, M, S) do { \
  const float w0_ = fmaf(A0, P0.x, fmaf(A1, P0.y, fmaf(A2, P0.z, T0))); \
  const float w1_ = fmaf(A0, P1.x, fmaf(A1, P1.y, fmaf(A2, P1.z, T1))); \
  const float w2_ = fmaf(A0, P2.x, fmaf(A1, P2.y, fmaf(A2, P2.z, T2))); \
  const float w3_ = fmaf(A0, P3.x, fmaf(A1, P3.y, fmaf(A2, P3.z, T3))); \
  const float mc_ = fmaxf(fmaxf(w0_, w1_), fmaxf(w2_, w3_)); \
  const float mn_ = fmaxf(M, mc_); \
  const float rr_ = __builtin_amdgcn_exp2f(M - mn_); \
  const float e0_ = __builtin_amdgcn_exp2f(w0_ - mn_); \
  const float e1_ = __builtin_amdgcn_exp2f(w1_ - mn_); \
  const float e2_ = __builtin_amdgcn_exp2f(w2_ - mn_); \
  const float e3_ = __builtin_amdgcn_exp2f(w3_ - mn_); \
  S = fmaf(S, rr_, (e0_ + e1_) + (e2_ + e3_)); \
  M = mn_; \
} while(0)

// Fused pre-scaled per-eps tables: sA[r]=(sc*y0,sc*y1,sc*y2, tf),
// sB[r]=(sc*x0,sc*x1,sc*x2, tg), sC[r]=(tq, tp);
// tf=sc*(g+yh)+lA, tg=sc*(f+xh)+lA, tp=sc*(px+xh)+lA, tq=sc*(py+yh)+lA.
// Row-side -0.5|.|^2*sc cancels in exp2, re-added at finalize.
// Wave-private LDS regions + same-wave DS program order -> zero barriers.
__global__ __launch_bounds__(256, 4) void sinkhorn_kernel(
    const float* __restrict__ pred, const float* __restrict__ pc,
    float* __restrict__ partial)
{
    __shared__ float4 sA[NROWS];
    __shared__ float4 sB[NROWS];
    __shared__ float2 sC[NROWS];

    const int b    = blockIdx.x;
    const int wv   = threadIdx.x >> 6;
    const int lane = threadIdx.x & 63;
    const int w    = (wv + b) & 3;     // slot id (rotated per block)
    const int rb   = w << 8;           // LDS region base (by slot)

    int pj = -1;
    const int np = c_w_np[w];
    #pragma unroll
    for (int j = 0; j < 6; ++j)
        if (j < np && lane >= c_w_lane0[w][j] && lane < c_w_lane0[w][j+1]) pj = j;
    const bool lact = (pj >= 0);
    const int jj   = lact ? pj : 0;
    const int part = c_w_part[w][jj];
    const int st   = c_start[part];
    const int n    = lact ? c_n[part] : 0;
    const int h    = (n + 3) >> 2;          // chunks (and lanes) per part
    const int r0   = lact ? (lane - c_w_lane0[w][jj]) : 0;
    const int tb   = rb + c_w_tb[w][jj];

    float x0r[4],x1r[4],x2r[4],y0r[4],y1r[4],y2r[4],xh[4],yh[4];
    bool ra[4];
    #pragma unroll
    for (int j=0;j<4;++j) {
        const int r = r0 + j*h;
        ra[j] = lact && (r < n);
        float a0=0.f,a1=0.f,a2=0.f,b0=0.f,b1=0.f,b2=0.f;
        if (ra[j]) {
            const float* xp = pred + ((size_t)b*TOTALV + st + r)*3;
            const float* yp = pc   + ((size_t)b*TOTALV + st + r)*3;
            a0=xp[0]; a1=xp[1]; a2=xp[2];
            b0=yp[0]; b1=yp[1]; b2=yp[2];
        }
        x0r[j]=a0; x1r[j]=a1; x2r[j]=a2;
        y0r[j]=b0; y1r[j]=b1; y2r[j]=b2;
        xh[j] = -0.5f*(a0*a0+a1*a1+a2*a2);
        yh[j] = -0.5f*(b0*b0+b1*b1+b2*b2);
    }

    const float lA = lact ? -log2f((float)n) : 0.f;
    float f[4]={0,0,0,0}, g[4]={0,0,0,0}, px[4]={0,0,0,0}, py[4]={0,0,0,0};

    #pragma unroll 1
    for (int it=0; it<NEPS; ++it) {
        const float eps = c_eps[it];
        const float sc  = LOG2E/eps;
        const float ce  = -eps*LN2;

        // write fused scaled tables (pre-update f,g,px,py: matches reference order)
        #pragma unroll
        for (int j=0;j<4;++j) if (lact) {
            const int tr = tb + r0 + j*h;
            if (ra[j]) {
                sA[tr] = make_float4(y0r[j]*sc, y1r[j]*sc, y2r[j]*sc, fmaf(sc, g[j]  + yh[j], lA));
                sB[tr] = make_float4(x0r[j]*sc, x1r[j]*sc, x2r[j]*sc, fmaf(sc, f[j]  + xh[j], lA));
                sC[tr] = make_float2(fmaf(sc, py[j] + yh[j], lA), fmaf(sc, px[j] + xh[j], lA));
            } else {
                sA[tr] = make_float4(0.f, 0.f, 0.f, NEGBIG);
                sB[tr] = make_float4(0.f, 0.f, 0.f, NEGBIG);
                sC[tr] = make_float2(NEGBIG, NEGBIG);
            }
        }

        float mF[4],mG[4],mP[4],mQ[4],sF[4],sG[4],sP[4],sQ[4];
        #pragma unroll
        for (int j=0;j<4;++j) {
            mF[j]=-INFINITY; mG[j]=-INFINITY; mP[j]=-INFINITY; mQ[j]=-INFINITY;
            sF[j]=0.f; sG[j]=0.f; sP[j]=0.f; sQ[j]=0.f;
        }

        #pragma unroll 1
        for (int cc=0; cc<h; ++cc) {
            const int row = tb + (cc<<2);
            // batch all loads up front (one lgkmcnt window); sB prefetched
            const float4 a0 = sA[row+0], a1 = sA[row+1], a2 = sA[row+2], a3 = sA[row+3];
            const float2 c0 = sC[row+0], c1 = sC[row+1], c2 = sC[row+2], c3 = sC[row+3];
            const float4 b0 = sB[row+0], b1 = sB[row+1], b2 = sB[row+2], b3 = sB[row+3];
            // phase A: ft (x·cy + tf), py (y·cy + tq) — consumes a*, c*.x
            #pragma unroll
            for (int j=0;j<4;++j) {
                SU(x0r[j],x1r[j],x2r[j], a0,a1,a2,a3, a0.w,a1.w,a2.w,a3.w, mF[j], sF[j]);
                SU(y0r[j],y1r[j],y2r[j], a0,a1,a2,a3, c0.x,c1.x,c2.x,c3.x, mQ[j], sQ[j]);
            }
            // phase B: gt (y·cx + tg), px (x·cx + tp) — consumes b*, c*.y
            #pragma unroll
            for (int j=0;j<4;++j) {
                SU(y0r[j],y1r[j],y2r[j], b0,b1,b2,b3, b0.w,b1.w,b2.w,b3.w, mG[j], sG[j]);
                SU(x0r[j],x1r[j],x2r[j], b0,b1,b2,b3, c0.y,c1.y,c2.y,c3.y, mP[j], sP[j]);
            }
        }

        if (lact) {
            #pragma unroll
            for (int j=0;j<4;++j) {
                const float ax = xh[j]*sc, ay = yh[j]*sc;
                f[j]  = 0.5f*(f[j]  + ce*(ax + mF[j] + __builtin_amdgcn_logf(sF[j])));
                g[j]  = 0.5f*(g[j]  + ce*(ay + mG[j] + __builtin_amdgcn_logf(sG[j])));
                px[j] = 0.5f*(px[j] + ce*(ax + mP[j] + __builtin_amdgcn_logf(sP[j])));
                py[j] = 0.5f*(py[j] + ce*(ay + mQ[j] + __builtin_amdgcn_logf(sQ[j])));
            }
        }
    }

    float d = 0.f;
    #pragma unroll
    for (int j=0;j<4;++j) if (ra[j]) d += (f[j]-px[j]) + (g[j]-py[j]);
    if (lact) d *= 1.0f/(float)n;
    #pragma unroll
    for (int o=32;o>0;o>>=1) d += __shfl_down(d, o, 64);
    if (lane==0) partial[(b<<2)+wv] = d * (1.0f/(float)BATCH);
}

__global__ __launch_bounds__(1024) void reduce_kernel(
    const float* __restrict__ partial, float* __restrict__ out, int nb)
{
    const int t = threadIdx.x;
    double acc = 0.0;
    for (int i=t; i<nb; i+=blockDim.x) acc += (double)partial[i];
    #pragma unroll
    for (int o=32; o>0; o>>=1) acc += __shfl_down(acc, o, 64);
    __shared__ double ws[16];
    if ((t & 63) == 0) ws[t >> 6] = acc;
    __syncthreads();
    if (t == 0) {
        double tot = 0.0;
        for (int v=0; v<1024/64; ++v) tot += ws[v];
        out[0] = (float)tot;
    }
}

extern "C" void kernel_launch(void* const* d_in, const int* in_sizes, int n_in,
                              void* d_out, int out_size, void* d_ws, size_t ws_size,
                              hipStream_t stream) {
    const float* pred = (const float*)d_in[0];
    const float* pc   = (const float*)d_in[1];
    float* partial = (float*)d_ws;                  // BATCH*4 floats = 32 KB
    float* out     = (float*)d_out;
    sinkhorn_kernel<<<BATCH, 256, 0, stream>>>(pred, pc, partial);
    reduce_kernel<<<1, 1024, 0, stream>>>(partial, out, BATCH*4);
}